// Round 1
// baseline (94.245 us; speedup 1.0000x reference)
//
#include <hip/hip_runtime.h>

// BatchAllTripletLoss on MI355X.
// Key insight: mask[p,n] != 0 only at n = p^256, so the 512^3 cube collapses to
// t(a,p) = relu(d(a,p) - d(a,p^256) + 1) over the 512x512 (a,p) grid.
// Outputs (5 f32 scalars): loss, mean(differences)=0 (exact cancellation),
// good = M^3 - M^2 + #(t<1e-5), bad = M^2 - #(t<1e-5), sqrt(mean_norm_sq).

#define NHALF 256
#define M 512
#define DDIM 512
#define KC 32
#define LDA (KC + 4)   // row pad: keeps float4 16B alignment (36*4=144 B rows), <=2-way bank aliasing (free)

struct Stats {
    float sum_pos;        // sum of t where t > 1e-5
    unsigned int cnt_pos; // #(t > 1e-5)
    unsigned int cnt_lt;  // #(t < 1e-5) among masked entries
};

__device__ __forceinline__ const float* row_ptr(const float* __restrict__ h1,
                                                const float* __restrict__ h2, int r) {
    return (r < NHALF) ? (h1 + (size_t)r * DDIM) : (h2 + (size_t)(r - NHALF) * DDIM);
}

__device__ __forceinline__ float distf(float n2a, float n2b, float g) {
    float sq = n2a + n2b - 2.0f * g;
    sq = fmaxf(sq, 0.0f);
    float d = (sq > 0.0f) ? sqrtf(sq) : 0.0f;
    return fmaxf(d, 1e-7f);   // torch.clamp(min=1e-7)
}

// ---------------- Kernel 1: row norms + zero stats ----------------
__global__ __launch_bounds__(64) void norms_kernel(const float* __restrict__ h1,
                                                   const float* __restrict__ h2,
                                                   float* __restrict__ n2,
                                                   Stats* __restrict__ st) {
    const int row = blockIdx.x;
    const float* p = row_ptr(h1, h2, row);
    const int lane = threadIdx.x;
    float s = 0.0f;
#pragma unroll
    for (int k = lane; k < DDIM; k += 64) {
        float v = p[k];
        s = fmaf(v, v, s);
    }
#pragma unroll
    for (int off = 32; off > 0; off >>= 1) s += __shfl_down(s, off, 64);
    if (lane == 0) n2[row] = s;
    if (row == 0 && lane == 0) {
        st->sum_pos = 0.0f;
        st->cnt_pos = 0u;
        st->cnt_lt = 0u;
    }
}

// ---------------- Kernel 2: Gram tiles + triplet stats ----------------
// Block = (16,16). Computes A-tile rows [a0,a0+16) against column tiles
// [p0,p0+32) (B) and [p0+256,p0+288) (C). Emits t-stats for BOTH column
// ranges (sibling symmetry), so each (a,p) is covered exactly once by
// grid (8 p-tiles over [0,256), 32 a-tiles).
__global__ __launch_bounds__(256) void tile_kernel(const float* __restrict__ h1,
                                                   const float* __restrict__ h2,
                                                   const float* __restrict__ n2,
                                                   Stats* __restrict__ st) {
    __shared__ float As[16][LDA];
    __shared__ float Bs[32][LDA];
    __shared__ float Cs[32][LDA];

    const int tx = threadIdx.x;         // 0..15
    const int ty = threadIdx.y;         // 0..15
    const int tid = ty * 16 + tx;
    const int a0 = blockIdx.y * 16;
    const int p0 = blockIdx.x * 32;     // p0 in [0,256)
    const int q0 = p0 + NHALF;

    const int lrow_b = tid >> 3;            // 0..31 (B/C tile row)
    const int lcol   = (tid & 7) * 4;       // float4 column
    const int lrow_a = (tid & 127) >> 3;    // 0..15 (A tile row, first 128 threads)

    const float* arow = row_ptr(h1, h2, a0 + lrow_a);
    const float* brow = row_ptr(h1, h2, p0 + lrow_b);
    const float* crow = row_ptr(h1, h2, q0 + lrow_b);

    float gb0 = 0.0f, gb1 = 0.0f, gc0 = 0.0f, gc1 = 0.0f;

    for (int k0 = 0; k0 < DDIM; k0 += KC) {
        if (tid < 128) {
            *(float4*)&As[lrow_a][lcol] = *(const float4*)(arow + k0 + lcol);
        }
        *(float4*)&Bs[lrow_b][lcol] = *(const float4*)(brow + k0 + lcol);
        *(float4*)&Cs[lrow_b][lcol] = *(const float4*)(crow + k0 + lcol);
        __syncthreads();
#pragma unroll
        for (int k = 0; k < KC; k += 4) {
            float4 av = *(const float4*)&As[ty][k];
            float4 b0 = *(const float4*)&Bs[tx][k];
            float4 b1 = *(const float4*)&Bs[tx + 16][k];
            float4 c0 = *(const float4*)&Cs[tx][k];
            float4 c1 = *(const float4*)&Cs[tx + 16][k];
            gb0 = fmaf(av.x, b0.x, gb0); gb0 = fmaf(av.y, b0.y, gb0);
            gb0 = fmaf(av.z, b0.z, gb0); gb0 = fmaf(av.w, b0.w, gb0);
            gb1 = fmaf(av.x, b1.x, gb1); gb1 = fmaf(av.y, b1.y, gb1);
            gb1 = fmaf(av.z, b1.z, gb1); gb1 = fmaf(av.w, b1.w, gb1);
            gc0 = fmaf(av.x, c0.x, gc0); gc0 = fmaf(av.y, c0.y, gc0);
            gc0 = fmaf(av.z, c0.z, gc0); gc0 = fmaf(av.w, c0.w, gc0);
            gc1 = fmaf(av.x, c1.x, gc1); gc1 = fmaf(av.y, c1.y, gc1);
            gc1 = fmaf(av.z, c1.z, gc1); gc1 = fmaf(av.w, c1.w, gc1);
        }
        __syncthreads();
    }

    const int a = a0 + ty;
    const int p = p0 + tx;
    const float n2a  = n2[a];
    const float d_b0 = distf(n2a, n2[p],               gb0);
    const float d_b1 = distf(n2a, n2[p + 16],          gb1);
    const float d_c0 = distf(n2a, n2[p + NHALF],       gc0);
    const float d_c1 = distf(n2a, n2[p + 16 + NHALF],  gc1);

    // t for (a,p)=d_b - d_c + 1 ; t for (a,p+256)=d_c - d_b + 1
    float t[4];
    t[0] = fmaxf(d_b0 - d_c0 + 1.0f, 0.0f);
    t[1] = fmaxf(d_c0 - d_b0 + 1.0f, 0.0f);
    t[2] = fmaxf(d_b1 - d_c1 + 1.0f, 0.0f);
    t[3] = fmaxf(d_c1 - d_b1 + 1.0f, 0.0f);

    float lsum = 0.0f;
    unsigned int lcp = 0u, lcl = 0u;
#pragma unroll
    for (int i = 0; i < 4; ++i) {
        if (t[i] > 1e-5f) { lsum += t[i]; lcp++; }
        if (t[i] < 1e-5f) lcl++;
    }

    // wave reduce (64 lanes), then cross-wave via LDS, one atomic triple per block
#pragma unroll
    for (int off = 32; off > 0; off >>= 1) {
        lsum += __shfl_down(lsum, off, 64);
        lcp  += __shfl_down(lcp,  off, 64);
        lcl  += __shfl_down(lcl,  off, 64);
    }
    __shared__ float    wsum[4];
    __shared__ unsigned wcp[4], wcl[4];
    const int lane = tid & 63, w = tid >> 6;
    if (lane == 0) { wsum[w] = lsum; wcp[w] = lcp; wcl[w] = lcl; }
    __syncthreads();
    if (tid == 0) {
        atomicAdd(&st->sum_pos, wsum[0] + wsum[1] + wsum[2] + wsum[3]);
        atomicAdd(&st->cnt_pos, wcp[0] + wcp[1] + wcp[2] + wcp[3]);
        atomicAdd(&st->cnt_lt,  wcl[0] + wcl[1] + wcl[2] + wcl[3]);
    }
}

// ---------------- Kernel 3: finalize 5 scalars ----------------
__global__ __launch_bounds__(64) void finalize_kernel(const float* __restrict__ n2,
                                                      const Stats* __restrict__ st,
                                                      float* __restrict__ out) {
    const int lane = threadIdx.x;
    float s = 0.0f;
#pragma unroll
    for (int k = lane; k < M; k += 64) s += n2[k];
#pragma unroll
    for (int off = 32; off > 0; off >>= 1) s += __shfl_down(s, off, 64);
    if (lane == 0) {
        const float mean_norm_sq = s / (float)M;
        const float mean_rel = st->sum_pos / (float)st->cnt_pos;
        out[0] = mean_rel + 1e-4f * mean_norm_sq;   // loss
        out[1] = 0.0f;                              // mean(differences): exact cancellation
        const unsigned int cl = st->cnt_lt;
        out[2] = (float)(133955584u + cl);          // good = M^3 - M^2 + cnt_lt
        out[3] = (float)(262144u - cl);             // bad  = M^2 - cnt_lt
        out[4] = sqrtf(mean_norm_sq);
    }
}

extern "C" void kernel_launch(void* const* d_in, const int* in_sizes, int n_in,
                              void* d_out, int out_size, void* d_ws, size_t ws_size,
                              hipStream_t stream) {
    const float* h1 = (const float*)d_in[0];
    const float* h2 = (const float*)d_in[1];
    // d_in[2] (h3) is unused by the reference computation.
    float* n2 = (float*)d_ws;                              // 512 floats
    Stats* st = (Stats*)((char*)d_ws + 2048);              // accumulators
    float* out = (float*)d_out;

    norms_kernel<<<M, 64, 0, stream>>>(h1, h2, n2, st);
    tile_kernel<<<dim3(NHALF / 32, M / 16), dim3(16, 16), 0, stream>>>(h1, h2, n2, st);
    finalize_kernel<<<1, 64, 0, stream>>>(n2, st, out);
}

// Round 2
// 66.062 us; speedup vs baseline: 1.4266x; 1.4266x over previous
//
#include <hip/hip_runtime.h>

// BatchAllTripletLoss, MFMA version.
// mask[p,n] != 0 only at n = p^256  =>  t(a,p) = relu(d(a,p) - d(a,p^256) + 1)
// over the 512x512 (a,p) grid. Gram = X·X^T via bf16 MFMA (threshold analysis:
// 2% relative slack absorbs bf16 rounding by >10x).
// Outputs: [loss, mean(differences)=0 exactly, good=133955584+cnt_lt,
//           bad=262144-cnt_lt, sqrt(mean_norm_sq)]

#define NHALF 256
#define M 512
#define DDIM 512

typedef __attribute__((ext_vector_type(8))) short bf16x8;   // 8 bf16 = 4 VGPRs
typedef __attribute__((ext_vector_type(4))) float f32x4;

__device__ __forceinline__ unsigned short f2bf_rne(float f) {
    unsigned int x = __float_as_uint(f);
    x += 0x7FFFu + ((x >> 16) & 1u);          // round-to-nearest-even
    return (unsigned short)(x >> 16);
}

__device__ __forceinline__ float distf(float n2a, float n2b, float g) {
    float sq = n2a + n2b - 2.0f * g;
    sq = fmaxf(sq, 0.0f);
    float d = (sq > 0.0f) ? sqrtf(sq) : 0.0f;
    return fmaxf(d, 1e-7f);                    // torch.clamp(min=1e-7)
}

// ---------- Kernel 1: f32->bf16 convert + exact f32 row norms ----------
// grid 256 x 256thr; thread = one float4 (65536 float4s total, 128 per row).
// Block covers exactly 2 rows (waves 0,1 -> row 2b; waves 2,3 -> row 2b+1).
__global__ __launch_bounds__(256) void prep_kernel(const float* __restrict__ h1,
                                                   const float* __restrict__ h2,
                                                   unsigned short* __restrict__ X,
                                                   float* __restrict__ n2) {
    const int idx = blockIdx.x * 256 + threadIdx.x;   // float4 index
    const float4 v = (idx < 32768) ? ((const float4*)h1)[idx]
                                   : ((const float4*)h2)[idx - 32768];
    ushort4 o;
    o.x = f2bf_rne(v.x); o.y = f2bf_rne(v.y);
    o.z = f2bf_rne(v.z); o.w = f2bf_rne(v.w);
    ((ushort4*)X)[idx] = o;

    float s = v.x * v.x + v.y * v.y + v.z * v.z + v.w * v.w;
#pragma unroll
    for (int off = 32; off > 0; off >>= 1) s += __shfl_down(s, off, 64);

    __shared__ float wsum[4];
    const int lane = threadIdx.x & 63, w = threadIdx.x >> 6;
    if (lane == 0) wsum[w] = s;
    __syncthreads();
    if (threadIdx.x == 0)   n2[blockIdx.x * 2]     = wsum[0] + wsum[1];
    if (threadIdx.x == 128) n2[blockIdx.x * 2 + 1] = wsum[2] + wsum[3];
}

// ---------- Kernel 2: bf16 MFMA Gram + triplet stats ----------
// grid (16 p-tiles, 16 a-tiles) x 128 thr (2 waves).
// Wave w: rows [a0+16w, a0+16w+16) x cols {p0..p0+16} (B) and siblings +256 (C).
// Fragment layout (m89-verified): A row = lane&15, k = (lane>>4)*8+j; C/D:
// col = lane&15, row = (lane>>4)*4 + reg.
__global__ __launch_bounds__(128) void gram_kernel(const unsigned short* __restrict__ X,
                                                   const float* __restrict__ n2,
                                                   float* __restrict__ psum,
                                                   unsigned int* __restrict__ pcp,
                                                   unsigned int* __restrict__ pcl) {
    const int tid  = threadIdx.x;
    const int wave = tid >> 6, lane = tid & 63;
    const int a0 = blockIdx.y * 32 + wave * 16;
    const int p0 = blockIdx.x * 16;            // in [0,256)

    const int rsel = lane & 15;
    const int koff = (lane >> 4) * 8;
    const unsigned short* pa = X + (size_t)(a0 + rsel) * DDIM + koff;
    const unsigned short* pb = X + (size_t)(p0 + rsel) * DDIM + koff;
    const unsigned short* pc = X + (size_t)(p0 + NHALF + rsel) * DDIM + koff;

    f32x4 accB = {0.f, 0.f, 0.f, 0.f};
    f32x4 accC = {0.f, 0.f, 0.f, 0.f};
#pragma unroll
    for (int k0 = 0; k0 < DDIM; k0 += 32) {
        bf16x8 av = *(const bf16x8*)(pa + k0);
        bf16x8 bv = *(const bf16x8*)(pb + k0);
        bf16x8 cv = *(const bf16x8*)(pc + k0);
        accB = __builtin_amdgcn_mfma_f32_16x16x32_bf16(av, bv, accB, 0, 0, 0);
        accC = __builtin_amdgcn_mfma_f32_16x16x32_bf16(av, cv, accC, 0, 0, 0);
    }

    // epilogue: lane holds (a = a0 + quad*4 + r, p = p0 + (lane&15))
    const int quad = lane >> 4;
    const int pcol = p0 + (lane & 15);
    const float n2b = n2[pcol];
    const float n2c = n2[pcol + NHALF];
    float lsum = 0.0f;
    unsigned int lcp = 0u, lcl = 0u;
#pragma unroll
    for (int r = 0; r < 4; ++r) {
        const float n2a = n2[a0 + quad * 4 + r];
        const float db = distf(n2a, n2b, accB[r]);
        const float dc = distf(n2a, n2c, accC[r]);
        const float t0 = fmaxf(db - dc + 1.0f, 0.0f);   // (a, p)
        const float t1 = fmaxf(dc - db + 1.0f, 0.0f);   // (a, p+256)
        if (t0 > 1e-5f) { lsum += t0; lcp++; }
        if (t0 < 1e-5f) lcl++;
        if (t1 > 1e-5f) { lsum += t1; lcp++; }
        if (t1 < 1e-5f) lcl++;
    }

#pragma unroll
    for (int off = 32; off > 0; off >>= 1) {
        lsum += __shfl_down(lsum, off, 64);
        lcp  += __shfl_down(lcp,  off, 64);
        lcl  += __shfl_down(lcl,  off, 64);
    }
    __shared__ float    s_sum[2];
    __shared__ unsigned s_cp[2], s_cl[2];
    if (lane == 0) { s_sum[wave] = lsum; s_cp[wave] = lcp; s_cl[wave] = lcl; }
    __syncthreads();
    if (tid == 0) {
        const int b = blockIdx.y * gridDim.x + blockIdx.x;
        psum[b] = s_sum[0] + s_sum[1];
        pcp[b]  = s_cp[0] + s_cp[1];
        pcl[b]  = s_cl[0] + s_cl[1];
    }
}

// ---------- Kernel 3: reduce 256 partials + norms, write 5 scalars ----------
__global__ __launch_bounds__(256) void final_kernel(const float* __restrict__ n2,
                                                    const float* __restrict__ psum,
                                                    const unsigned int* __restrict__ pcp,
                                                    const unsigned int* __restrict__ pcl,
                                                    float* __restrict__ out) {
    const int t = threadIdx.x;
    float s = psum[t];
    unsigned int cp = pcp[t], cl = pcl[t];
    float ns = n2[t] + n2[t + NHALF];
#pragma unroll
    for (int off = 32; off > 0; off >>= 1) {
        s  += __shfl_down(s,  off, 64);
        cp += __shfl_down(cp, off, 64);
        cl += __shfl_down(cl, off, 64);
        ns += __shfl_down(ns, off, 64);
    }
    __shared__ float    w_s[4], w_ns[4];
    __shared__ unsigned w_cp[4], w_cl[4];
    const int lane = t & 63, w = t >> 6;
    if (lane == 0) { w_s[w] = s; w_ns[w] = ns; w_cp[w] = cp; w_cl[w] = cl; }
    __syncthreads();
    if (t == 0) {
        const float sum_pos = w_s[0] + w_s[1] + w_s[2] + w_s[3];
        const float sum_n2  = w_ns[0] + w_ns[1] + w_ns[2] + w_ns[3];
        const unsigned cpt = w_cp[0] + w_cp[1] + w_cp[2] + w_cp[3];
        const unsigned clt = w_cl[0] + w_cl[1] + w_cl[2] + w_cl[3];
        const float mean_norm_sq = sum_n2 / (float)M;
        out[0] = sum_pos / (float)cpt + 1e-4f * mean_norm_sq;  // loss
        out[1] = 0.0f;                                         // mean(differences)
        out[2] = (float)(133955584u + clt);                    // good
        out[3] = (float)(262144u - clt);                       // bad
        out[4] = sqrtf(mean_norm_sq);
    }
}

extern "C" void kernel_launch(void* const* d_in, const int* in_sizes, int n_in,
                              void* d_out, int out_size, void* d_ws, size_t ws_size,
                              hipStream_t stream) {
    const float* h1 = (const float*)d_in[0];
    const float* h2 = (const float*)d_in[1];
    // d_in[2] (h3) unused by the reference computation.
    char* w = (char*)d_ws;
    unsigned short* X  = (unsigned short*)w;                   // 512 KB bf16 X
    float* n2          = (float*)(w + 512 * 1024);             // 2 KB
    float* psum        = (float*)(w + 512 * 1024 + 2048);      // 1 KB
    unsigned int* pcp  = (unsigned int*)(w + 512 * 1024 + 3072);
    unsigned int* pcl  = (unsigned int*)(w + 512 * 1024 + 4096);
    float* out = (float*)d_out;

    prep_kernel<<<256, 256, 0, stream>>>(h1, h2, X, n2);
    gram_kernel<<<dim3(16, 16), 128, 0, stream>>>(X, n2, psum, pcp, pcl);
    final_kernel<<<1, 256, 0, stream>>>(n2, psum, pcp, pcl, out);
}